// Round 6
// baseline (716.933 us; speedup 1.0000x reference)
//
#include <hip/hip_runtime.h>

typedef unsigned short ushort_t;
typedef __attribute__((ext_vector_type(8))) short s8v;
typedef __attribute__((ext_vector_type(4))) float f4v;
typedef __attribute__((ext_vector_type(2))) float f2v;
typedef __attribute__((ext_vector_type(4))) unsigned int u32x4;

#define NNODE 4096
#define HID 256
#define CR_L 5.0f      // COORDS_RANGE / L = 15/3
#define ASTR 528       // A-tile row stride in bytes (33*16: aligned, bank-uniform)
#define ASTR16 (16 * ASTR)
#define NSTR 1056      // node-kernel stage-1 stride (66*16)
#define NSTR16 (16 * NSTR)

__device__ __forceinline__ unsigned int cvt2(float lo, float hi) {
  unsigned int r;
  asm("v_cvt_pk_bf16_f32 %0, %1, %2" : "=v"(r) : "v"(lo), "v"(hi));
  return r;  // D[15:0]=lo, D[31:16]=hi, RNE
}
__device__ __forceinline__ ushort_t cvt1(float v) {
  unsigned int r;
  asm("v_cvt_pk_bf16_f32 %0, %1, %2" : "=v"(r) : "v"(v), "v"(v));
  return (ushort_t)r;
}
__device__ __forceinline__ float fast_rcp(float x) {
  float r;
  asm("v_rcp_f32 %0, %1" : "=v"(r) : "v"(x));
  return r;
}
__device__ __forceinline__ float silu_f(float v) { return v * fast_rcp(1.0f + __expf(-v)); }
__device__ __forceinline__ float sigm_f(float v) { return fast_rcp(1.0f + __expf(-v)); }

// ---- 8-wave edge-GEMM helpers: wave covers 32 cols (nt in {0,1}) ----
__device__ __forceinline__ void loadB2(s8v bd[2], const char* base, int q) {
#pragma unroll
  for (int nt = 0; nt < 2; ++nt)
    bd[nt] = *(const s8v*)(base + nt * 8192 + q * 64);
}
__device__ __forceinline__ void mfma_step2(const char* Ath, int q, const s8v bc[2], f4v acc[4][2]) {
  s8v a[4];
#pragma unroll
  for (int mt = 0; mt < 4; ++mt)
    a[mt] = *(const s8v*)(Ath + mt * ASTR16 + q * 64);
#pragma unroll
  for (int mt = 0; mt < 4; ++mt)
#pragma unroll
    for (int nt = 0; nt < 2; ++nt)
      acc[mt][nt] = __builtin_amdgcn_mfma_f32_16x16x32_bf16(a[mt], bc[nt], acc[mt][nt], 0, 0, 0);
}

// legacy direct-global gemm (proj/node kernels — off the critical path)
__device__ __forceinline__ void gemm64(const char* Ath, const ushort_t* Bth, f4v acc[4][4]) {
#pragma unroll
  for (int ks = 0; ks < 8; ++ks) {
    s8v a[4], bb[4];
#pragma unroll
    for (int mt = 0; mt < 4; ++mt)
      a[mt] = *(const s8v*)(Ath + mt * ASTR16 + ks * 64);
#pragma unroll
    for (int nt = 0; nt < 4; ++nt)
      bb[nt] = *(const s8v*)(Bth + nt * 4096 + ks * 32);
#pragma unroll
    for (int mt = 0; mt < 4; ++mt)
#pragma unroll
      for (int nt = 0; nt < 4; ++nt)
        acc[mt][nt] = __builtin_amdgcn_mfma_f32_16x16x32_bf16(a[mt], bb[nt], acc[mt][nt], 0, 0, 0);
  }
}

// ---------------- weight transpose + bf16 convert ----------------
__global__ __launch_bounds__(256) void wconv_kernel(
    const float* __restrict__ We1, const float* __restrict__ We2,
    const float* __restrict__ Wc1, const float* __restrict__ Wn1,
    const float* __restrict__ Wn2, ushort_t* __restrict__ wt) {
  int gid = blockIdx.x * 256 + threadIdx.x;          // < 1376256
  int l = gid / 458752;
  int r = gid - l * 458752;
  float v;
  if (r < 131072) {
    int part = r >> 16; int rr = r & 65535; int nn = rr >> 8, k = rr & 255;
    v = We1[(l * 513 + part * 256 + k) * 256 + nn];
  } else if (r < 196608) {
    int rr = r - 131072; int nn = rr >> 8, k = rr & 255;
    v = We2[(l * 256 + k) * 256 + nn];
  } else if (r < 262144) {
    int rr = r - 196608; int nn = rr >> 8, k = rr & 255;
    v = Wc1[(l * 256 + k) * 256 + nn];
  } else if (r < 393216) {
    int rr = r - 262144; int nn = rr >> 9, k = rr & 511;
    v = Wn1[(l * 512 + k) * 256 + nn];
  } else {
    int rr = r - 393216; int nn = rr >> 8, k = rr & 255;
    v = Wn2[(l * 256 + k) * 256 + nn];
  }
  wt[gid] = cvt1(v);
}

// ---------------- time embedding + preconditioning ----------------
__global__ __launch_bounds__(256) void embed_kernel(
    const float* __restrict__ logt, const float* __restrict__ xs,
    const float* __restrict__ Wemb, const float* __restrict__ bemb,
    float* __restrict__ h, float* __restrict__ x0) {
  __shared__ float te[128];
  const int b = blockIdx.x, tid = threadIdx.x;
  const float lt = logt[b];
  if (tid < 64) {
    float fr = powf(1e-4f, (float)tid * (1.0f / 64.0f));
    float ang = lt * 0.25f * fr;
    te[tid] = cosf(ang);
    te[tid + 64] = sinf(ang);
  }
  float tt = expf(lt);
  float cin = 1.0f / sqrtf(0.25f + tt * tt);
  if (tid < 192) x0[b * 192 + tid] = xs[b * 192 + tid] * cin;
  __syncthreads();
  float acc = bemb[tid];
  for (int k = 0; k < 128; ++k) acc += te[k] * Wemb[k * 256 + tid];
  float* hp = h + (b * 64) * 256 + tid;
#pragma unroll 4
  for (int nn = 0; nn < 64; ++nn) hp[nn * 256] = acc;
}

// ---------------- per-node projections p_r = h@We1_r + be1, p_c = h@We1_c ----------------
__global__ __launch_bounds__(256) void proj_kernel(
    const float* __restrict__ h, const ushort_t* __restrict__ Bt0,
    const ushort_t* __restrict__ Bt1, const float* __restrict__ be1,
    float* __restrict__ p_r, float* __restrict__ p_c) {
  __shared__ u32x4 AbV[64 * ASTR / 16];
  char* Ab = (char*)AbV;
  const int t = threadIdx.x, lane = t & 63, w = t >> 6;
  const int al = lane & 15, ag = lane >> 4;
  const int R0 = blockIdx.x * 64;
  {
    const int j = t & 63, cc = t >> 6;
    const float4* hv = (const float4*)(h + (R0 + j) * 256) + cc * 16;
    u32x4* wb = (u32x4*)(Ab + j * ASTR + cc * 128);
#pragma unroll
    for (int g = 0; g < 8; ++g) {
      float4 v0 = hv[g * 2], v1 = hv[g * 2 + 1];
      u32x4 q;
      q[0] = cvt2(v0.x, v0.y); q[1] = cvt2(v0.z, v0.w);
      q[2] = cvt2(v1.x, v1.y); q[3] = cvt2(v1.z, v1.w);
      wb[g] = q;
    }
  }
  __syncthreads();
  const char* Ath = Ab + al * ASTR + ag * 16;
#pragma unroll 1
  for (int mat = 0; mat < 2; ++mat) {
    const ushort_t* Bth = (mat ? Bt1 : Bt0) + (w * 64 + al) * 256 + ag * 8;
    float* P = mat ? p_c : p_r;
    f4v acc[4][4];
#pragma unroll
    for (int mt = 0; mt < 4; ++mt)
#pragma unroll
      for (int nt = 0; nt < 4; ++nt) acc[mt][nt] = (f4v){0.f, 0.f, 0.f, 0.f};
    gemm64(Ath, Bth, acc);
#pragma unroll
    for (int mt = 0; mt < 4; ++mt)
#pragma unroll
      for (int nt = 0; nt < 4; ++nt) {
        int col = w * 64 + nt * 16 + al;
        float bias = mat ? 0.0f : be1[col];
#pragma unroll
        for (int r = 0; r < 4; ++r) {
          int row = mt * 16 + ag * 4 + r;
          P[(R0 + row) * 256 + col] = acc[mt][nt][r] + bias;
        }
      }
  }
}

// ---------------- fused edge kernel: one block per node (its 63 out-edges) ----------------
// 8 waves x 32 cols; B global->reg 3-deep pipeline; XCD-swizzled blockIdx (batch-per-XCD).
__global__ __launch_bounds__(512, 4) void edge_kernel(
    const float* __restrict__ x_in, float* __restrict__ x_out,
    const float* __restrict__ p_r, const float* __restrict__ p_c,
    const float* __restrict__ w_rad,
    const ushort_t* __restrict__ We2t, const float* __restrict__ be2,
    const float* __restrict__ Wa, const float* __restrict__ ba,
    const ushort_t* __restrict__ Wc1t, const float* __restrict__ bc1,
    const float* __restrict__ Wc2, float* __restrict__ agg) {
  __shared__ u32x4 AbV[64 * ASTR / 16];   // 33 KB A-tile (m1, then m2)
  char* Ab = (char*)AbV;
  __shared__ float dn[64][3];
  __shared__ float attv[64];
  __shared__ float red[8][64];
  __shared__ float trv[64];

  const int t = threadIdx.x;
  // XCD swizzle: dispatch d -> XCD d%8; batches 8x..8x+7 all live on XCD x.
  const int node = ((blockIdx.x & 7) << 9) | (blockIdx.x >> 3);
  const int b = node >> 6, n = node & 63;
  const int lane = t & 63, w = t >> 6;          // w in [0,8): col strip w*32..+32
  const int al = lane & 15, ag = lane >> 4;

  const char* bWe2 = (const char*)We2t + ((w * 32 + al) * 256 + ag * 8) * 2;
  const char* bWc1 = (const char*)Wc1t + ((w * 32 + al) * 256 + ag * 8) * 2;

  s8v b0[2], b1[2], b2[2];
  loadB2(b0, bWe2, 0);   // prefetch GEMM1 panels 0..2 — hide under all of phase 1
  loadB2(b1, bWe2, 1);
  loadB2(b2, bWe2, 2);

  // ---- phase 1: geometry (redundant per wave) + m1 -> Ab (rows j, cols w*32..+32) ----
  {
    const int j = lane;
    const bool live = j < 63;
    const int cl = j < n ? j : j + 1;
    const int nb = (b << 6) + cl;
    const float xi0 = x_in[node * 3], xi1 = x_in[node * 3 + 1], xi2 = x_in[node * 3 + 2];
    const float d0 = xi0 - x_in[nb * 3], d1 = xi1 - x_in[nb * 3 + 1], d2 = xi2 - x_in[nb * 3 + 2];
    const float r2 = d0 * d0 + d1 * d1 + d2 * d2;
    const float inv = fast_rcp(sqrtf(r2 + 1e-8f) + 1.0f);
    if (t < 63) { dn[t][0] = d0 * inv; dn[t][1] = d1 * inv; dn[t][2] = d2 * inv; }
    const float rj = live ? r2 : 0.0f;
    const float4* prv = (const float4*)(p_r + (node << 8)) + w * 8;
    const float4* pcv = (const float4*)(p_c + (nb << 8)) + w * 8;
    const float4* wrv = (const float4*)w_rad + w * 8;
    u32x4* wb = (u32x4*)(Ab + j * ASTR + w * 64);
#pragma unroll
    for (int g = 0; g < 4; ++g) {
      u32x4 q = {0u, 0u, 0u, 0u};
      if (live) {
        float4 a0 = prv[g * 2], a1 = prv[g * 2 + 1];
        float4 bq = pcv[g * 2], b1q = pcv[g * 2 + 1];
        float4 w0 = wrv[g * 2], w1 = wrv[g * 2 + 1];
        float v0 = silu_f(a0.x + bq.x + rj * w0.x);
        float v1 = silu_f(a0.y + bq.y + rj * w0.y);
        float v2 = silu_f(a0.z + bq.z + rj * w0.z);
        float v3 = silu_f(a0.w + bq.w + rj * w0.w);
        float v4 = silu_f(a1.x + b1q.x + rj * w1.x);
        float v5 = silu_f(a1.y + b1q.y + rj * w1.y);
        float v6 = silu_f(a1.z + b1q.z + rj * w1.z);
        float v7 = silu_f(a1.w + b1q.w + rj * w1.w);
        q[0] = cvt2(v0, v1); q[1] = cvt2(v2, v3);
        q[2] = cvt2(v4, v5); q[3] = cvt2(v6, v7);
      }
      wb[g] = q;
    }
  }
  __syncthreads();   // S1: m1 visible

  const char* Ath = Ab + al * ASTR + ag * 16;

  // ---- GEMM1: g1 = m1 @ We2 — barrier-free, 3-deep reg-pipelined B ----
  f4v acc[4][2];
#pragma unroll
  for (int mt = 0; mt < 4; ++mt)
#pragma unroll
    for (int nt = 0; nt < 2; ++nt) acc[mt][nt] = (f4v){0.f, 0.f, 0.f, 0.f};
  mfma_step2(Ath, 0, b0, acc); loadB2(b0, bWe2, 3);
  mfma_step2(Ath, 1, b1, acc); loadB2(b1, bWe2, 4);
  mfma_step2(Ath, 2, b2, acc); loadB2(b2, bWe2, 5);
  mfma_step2(Ath, 3, b0, acc); loadB2(b0, bWe2, 6);
  mfma_step2(Ath, 4, b1, acc); loadB2(b1, bWe2, 7);
  mfma_step2(Ath, 5, b2, acc); loadB2(b2, bWc1, 0);   // prefetch GEMM2 panels
  mfma_step2(Ath, 6, b0, acc); loadB2(b0, bWc1, 1);
  mfma_step2(Ath, 7, b1, acc); loadB2(b1, bWc1, 2);

  // ---- epilogue1a (regs only): m2 = silu(g1+be2); attention partials + reduce ----
  {
    float bb2[2], wa4[2];
#pragma unroll
    for (int nt = 0; nt < 2; ++nt) {
      int col = w * 32 + nt * 16 + al;
      bb2[nt] = be2[col]; wa4[nt] = Wa[col];
    }
    float attp[4][4];
#pragma unroll
    for (int mt = 0; mt < 4; ++mt) {
#pragma unroll
      for (int r = 0; r < 4; ++r) attp[mt][r] = 0.0f;
#pragma unroll
      for (int nt = 0; nt < 2; ++nt) {
#pragma unroll
        for (int r = 0; r < 4; ++r) {
          float v = silu_f(acc[mt][nt][r] + bb2[nt]);
          acc[mt][nt][r] = v;
          attp[mt][r] += v * wa4[nt];
        }
      }
    }
#pragma unroll
    for (int off = 1; off < 16; off <<= 1)
#pragma unroll
      for (int mt = 0; mt < 4; ++mt)
#pragma unroll
        for (int r = 0; r < 4; ++r) attp[mt][r] += __shfl_xor(attp[mt][r], off);
    __syncthreads();   // S2: all waves done reading m1 from Ab
    // ---- epilogue1b: write m2 -> Ab (bf16) and att partials -> red ----
    char* mwb = Ab + (ag * 4) * ASTR + (w * 32 + al) * 2;
#pragma unroll
    for (int mt = 0; mt < 4; ++mt)
#pragma unroll
      for (int nt = 0; nt < 2; ++nt)
#pragma unroll
        for (int r = 0; r < 4; ++r)
          *(ushort_t*)(mwb + mt * ASTR16 + r * ASTR + nt * 32) = cvt1(acc[mt][nt][r]);
    if (al == 0) {
#pragma unroll
      for (int mt = 0; mt < 4; ++mt)
#pragma unroll
        for (int r = 0; r < 4; ++r) red[w][mt * 16 + ag * 4 + r] = attp[mt][r];
    }
  }
  __syncthreads();     // S3: m2 + red ready
  if (t < 64) {
    float s = red[0][t] + red[1][t] + red[2][t] + red[3][t] +
              red[4][t] + red[5][t] + red[6][t] + red[7][t] + ba[0];
    attv[t] = (t < 63) ? sigm_f(s) : 0.0f;   // mask padded row 63
  }
  __syncthreads();     // S4: attv ready

  // ---- agg column sums (att applied in f32 from regs) ----
  {
    float aggp[2] = {0.f, 0.f};
#pragma unroll
    for (int mt = 0; mt < 4; ++mt) {
      float a0 = attv[mt * 16 + ag * 4 + 0], a1 = attv[mt * 16 + ag * 4 + 1];
      float a2 = attv[mt * 16 + ag * 4 + 2], a3 = attv[mt * 16 + ag * 4 + 3];
#pragma unroll
      for (int nt = 0; nt < 2; ++nt)
        aggp[nt] += a0 * acc[mt][nt][0] + a1 * acc[mt][nt][1] +
                    a2 * acc[mt][nt][2] + a3 * acc[mt][nt][3];
    }
#pragma unroll
    for (int nt = 0; nt < 2; ++nt) {
      aggp[nt] += __shfl_xor(aggp[nt], 16);
      aggp[nt] += __shfl_xor(aggp[nt], 32);
    }
    if (ag < 2)
      agg[(node << 8) + w * 32 + ag * 16 + al] = (ag == 0) ? aggp[0] : aggp[1];
  }

  // ---- GEMM2: g2 = m2 @ Wc1 — barrier-free (gate folded into epilogue) ----
#pragma unroll
  for (int mt = 0; mt < 4; ++mt)
#pragma unroll
    for (int nt = 0; nt < 2; ++nt) acc[mt][nt] = (f4v){0.f, 0.f, 0.f, 0.f};
  mfma_step2(Ath, 0, b2, acc); loadB2(b2, bWc1, 3);
  mfma_step2(Ath, 1, b0, acc); loadB2(b0, bWc1, 4);
  mfma_step2(Ath, 2, b1, acc); loadB2(b1, bWc1, 5);
  mfma_step2(Ath, 3, b2, acc); loadB2(b2, bWc1, 6);
  mfma_step2(Ath, 4, b0, acc); loadB2(b0, bWc1, 7);
  mfma_step2(Ath, 5, b1, acc);
  mfma_step2(Ath, 6, b2, acc);
  mfma_step2(Ath, 7, b0, acc);

  // ---- epilogue 2: s = silu(att*g2 + bc1); tr-partials = s . Wc2 ----
  {
    float b3[2], wc4[2];
#pragma unroll
    for (int nt = 0; nt < 2; ++nt) {
      int col = w * 32 + nt * 16 + al;
      b3[nt] = bc1[col]; wc4[nt] = Wc2[col];
    }
    float trp[4][4];
#pragma unroll
    for (int mt = 0; mt < 4; ++mt) {
      float a0 = attv[mt * 16 + ag * 4 + 0], a1 = attv[mt * 16 + ag * 4 + 1];
      float a2 = attv[mt * 16 + ag * 4 + 2], a3 = attv[mt * 16 + ag * 4 + 3];
#pragma unroll
      for (int r = 0; r < 4; ++r) trp[mt][r] = 0.0f;
#pragma unroll
      for (int nt = 0; nt < 2; ++nt) {
        trp[mt][0] += silu_f(a0 * acc[mt][nt][0] + b3[nt]) * wc4[nt];
        trp[mt][1] += silu_f(a1 * acc[mt][nt][1] + b3[nt]) * wc4[nt];
        trp[mt][2] += silu_f(a2 * acc[mt][nt][2] + b3[nt]) * wc4[nt];
        trp[mt][3] += silu_f(a3 * acc[mt][nt][3] + b3[nt]) * wc4[nt];
      }
    }
#pragma unroll
    for (int off = 1; off < 16; off <<= 1)
#pragma unroll
      for (int mt = 0; mt < 4; ++mt)
#pragma unroll
        for (int r = 0; r < 4; ++r) trp[mt][r] += __shfl_xor(trp[mt][r], off);
    if (al == 0) {
#pragma unroll
      for (int mt = 0; mt < 4; ++mt)
#pragma unroll
        for (int r = 0; r < 4; ++r) red[w][mt * 16 + ag * 4 + r] = trp[mt][r];
    }
  }
  __syncthreads();     // S5: red2 ready
  if (t < 64) {
    float s = red[0][t] + red[1][t] + red[2][t] + red[3][t] +
              red[4][t] + red[5][t] + red[6][t] + red[7][t];
    trv[t] = tanhf(s) * CR_L;
  }
  __syncthreads();     // S6: trv ready

  // ---- x_out[i] = x_in[i] + sum_j dn[j]*tr[j] ----
  if (t < 64) {
    float vx = 0.f, vy = 0.f, vz = 0.f;
    if (t < 63) {
      float tj = trv[t];
      vx = dn[t][0] * tj; vy = dn[t][1] * tj; vz = dn[t][2] * tj;
    }
#pragma unroll
    for (int off = 1; off < 64; off <<= 1) {
      vx += __shfl_xor(vx, off);
      vy += __shfl_xor(vy, off);
      vz += __shfl_xor(vz, off);
    }
    if (t == 0) {
      x_out[node * 3 + 0] = x_in[node * 3 + 0] + vx;
      x_out[node * 3 + 1] = x_in[node * 3 + 1] + vy;
      x_out[node * 3 + 2] = x_in[node * 3 + 2] + vz;
    }
  }
}

// ---------------- node update: h += silu([h||agg]@Wn1+bn1)@Wn2+bn2 ----------------
__global__ __launch_bounds__(256) void node_kernel(
    float* __restrict__ h, const float* __restrict__ agg,
    const ushort_t* __restrict__ Wn1t, const float* __restrict__ bn1,
    const ushort_t* __restrict__ Wn2t, const float* __restrict__ bn2) {
  __shared__ u32x4 AbV[64 * NSTR / 16];   // 66KB: A1 [64][512]@1056B, reused as A2 [64][256]@528B
  char* Ab = (char*)AbV;
  const int t = threadIdx.x, lane = t & 63, w = t >> 6;
  const int al = lane & 15, ag = lane >> 4;
  const int R0 = blockIdx.x * 64;
  {
    const int j = t & 63, cc = t >> 6;
    u32x4* wb = (u32x4*)(Ab + j * NSTR + cc * 256);
#pragma unroll
    for (int g = 0; g < 16; ++g) {
      int c0 = cc * 128 + g * 8;
      const float* src = (c0 < 256) ? (h + (R0 + j) * 256 + c0)
                                    : (agg + (R0 + j) * 256 + (c0 - 256));
      float4 v0 = *(const float4*)src;
      float4 v1 = *(const float4*)(src + 4);
      u32x4 q;
      q[0] = cvt2(v0.x, v0.y); q[1] = cvt2(v0.z, v0.w);
      q[2] = cvt2(v1.x, v1.y); q[3] = cvt2(v1.z, v1.w);
      wb[g] = q;
    }
  }
  __syncthreads();
  // GEMM-A: K=512
  const char* AthN = Ab + al * NSTR + ag * 16;
  const ushort_t* BthA = Wn1t + (w * 64 + al) * 512 + ag * 8;
  f4v acc[4][4];
#pragma unroll
  for (int mt = 0; mt < 4; ++mt)
#pragma unroll
    for (int nt = 0; nt < 4; ++nt) acc[mt][nt] = (f4v){0.f, 0.f, 0.f, 0.f};
#pragma unroll
  for (int ks = 0; ks < 16; ++ks) {
    s8v a[4], bb[4];
#pragma unroll
    for (int mt = 0; mt < 4; ++mt)
      a[mt] = *(const s8v*)(AthN + mt * NSTR16 + ks * 64);
#pragma unroll
    for (int nt = 0; nt < 4; ++nt)
      bb[nt] = *(const s8v*)(BthA + nt * 8192 + ks * 32);
#pragma unroll
    for (int mt = 0; mt < 4; ++mt)
#pragma unroll
      for (int nt = 0; nt < 4; ++nt)
        acc[mt][nt] = __builtin_amdgcn_mfma_f32_16x16x32_bf16(a[mt], bb[nt], acc[mt][nt], 0, 0, 0);
  }
  __syncthreads();
  // u = silu(. + bn1) -> A2 (528B stride)
  {
    float bn1c[4];
#pragma unroll
    for (int nt = 0; nt < 4; ++nt) bn1c[nt] = bn1[w * 64 + nt * 16 + al];
    char* mwb = Ab + (ag * 4) * ASTR + (w * 64 + al) * 2;
#pragma unroll
    for (int mt = 0; mt < 4; ++mt)
#pragma unroll
      for (int nt = 0; nt < 4; ++nt)
#pragma unroll
        for (int r = 0; r < 4; ++r) {
          float v = silu_f(acc[mt][nt][r] + bn1c[nt]);
          *(ushort_t*)(mwb + mt * ASTR16 + r * ASTR + nt * 32) = cvt1(v);
        }
  }
  __syncthreads();
  // GEMM-B + residual
  const char* Ath2 = Ab + al * ASTR + ag * 16;
  const ushort_t* BthB = Wn2t + (w * 64 + al) * 256 + ag * 8;
#pragma unroll
  for (int mt = 0; mt < 4; ++mt)
#pragma unroll
    for (int nt = 0; nt < 4; ++nt) acc[mt][nt] = (f4v){0.f, 0.f, 0.f, 0.f};
  gemm64(Ath2, BthB, acc);
  {
    float bn2c[4];
#pragma unroll
    for (int nt = 0; nt < 4; ++nt) bn2c[nt] = bn2[w * 64 + nt * 16 + al];
#pragma unroll
    for (int mt = 0; mt < 4; ++mt)
#pragma unroll
      for (int nt = 0; nt < 4; ++nt) {
        int col = w * 64 + nt * 16 + al;
#pragma unroll
        for (int r = 0; r < 4; ++r) {
          int row = mt * 16 + ag * 4 + r;
          int idx = (R0 + row) * 256 + col;
          h[idx] = h[idx] + acc[mt][nt][r] + bn2c[nt];
        }
      }
  }
}

// ---------------- final: CoG removal + EDM output scaling ----------------
__global__ __launch_bounds__(64) void final_kernel(
    const float* __restrict__ logt, const float* __restrict__ xs,
    const float* __restrict__ xf, const float* __restrict__ x0,
    float* __restrict__ out) {
  const int b = blockIdx.x, t = threadIdx.x;
  float lt = logt[b], tt = expf(lt);
  float denom = 0.25f + tt * tt;
  float s1 = 0.25f / denom;
  float s2 = 0.5f * tt / sqrtf(denom);
  int node = b * 64 + t;
  float v0 = xf[node * 3 + 0] - x0[node * 3 + 0];
  float v1 = xf[node * 3 + 1] - x0[node * 3 + 1];
  float v2 = xf[node * 3 + 2] - x0[node * 3 + 2];
  float m0 = v0, m1 = v1, m2 = v2;
#pragma unroll
  for (int off = 1; off < 64; off <<= 1) {
    m0 += __shfl_xor(m0, off);
    m1 += __shfl_xor(m1, off);
    m2 += __shfl_xor(m2, off);
  }
  m0 *= (1.0f / 64.0f); m1 *= (1.0f / 64.0f); m2 *= (1.0f / 64.0f);
  out[b * 192 + t * 3 + 0] = xs[b * 192 + t * 3 + 0] * s1 + (v0 - m0) * s2;
  out[b * 192 + t * 3 + 1] = xs[b * 192 + t * 3 + 1] * s1 + (v1 - m1) * s2;
  out[b * 192 + t * 3 + 2] = xs[b * 192 + t * 3 + 2] * s1 + (v2 - m2) * s2;
}

extern "C" void kernel_launch(void* const* d_in, const int* in_sizes, int n_in,
                              void* d_out, int out_size, void* d_ws, size_t ws_size,
                              hipStream_t stream) {
  const float* logt = (const float*)d_in[0];
  const float* xs   = (const float*)d_in[1];
  const float* Wemb = (const float*)d_in[2];
  const float* bemb = (const float*)d_in[3];
  const float* We1  = (const float*)d_in[4];
  const float* be1  = (const float*)d_in[5];
  const float* We2  = (const float*)d_in[6];
  const float* be2  = (const float*)d_in[7];
  const float* Wa   = (const float*)d_in[8];
  const float* ba   = (const float*)d_in[9];
  const float* Wn1  = (const float*)d_in[10];
  const float* bn1  = (const float*)d_in[11];
  const float* Wn2  = (const float*)d_in[12];
  const float* bn2  = (const float*)d_in[13];
  const float* Wc1  = (const float*)d_in[14];
  const float* bc1  = (const float*)d_in[15];
  const float* Wc2  = (const float*)d_in[16];
  float* out = (float*)d_out;

  float* h   = (float*)d_ws;            // 4096*256
  float* pr  = h   + NNODE * HID;
  float* pc  = pr  + NNODE * HID;
  float* agg = pc  + NNODE * HID;
  float* x0  = agg + NNODE * HID;
  float* x1  = x0  + 12288;
  float* x2  = x1  + 12288;
  ushort_t* wt = (ushort_t*)(x2 + 12288);   // 1376256 bf16

  wconv_kernel<<<5376, 256, 0, stream>>>(We1, We2, Wc1, Wn1, Wn2, wt);
  embed_kernel<<<64, 256, 0, stream>>>(logt, xs, Wemb, bemb, h, x0);

  const float* xin = x0;
  float* xout = x1;
  for (int l = 0; l < 3; ++l) {
    const ushort_t* wl = wt + l * 458752;
    proj_kernel<<<64, 256, 0, stream>>>(h, wl, wl + 65536, be1 + l * 256, pr, pc);
    edge_kernel<<<4096, 512, 0, stream>>>(
        xin, xout, pr, pc,
        We1 + (l * 513 + 512) * 256,
        wl + 131072, be2 + l * 256,
        Wa + l * 256, ba + l,
        wl + 196608, bc1 + l * 256, Wc2 + l * 256, agg);
    node_kernel<<<64, 256, 0, stream>>>(h, agg, wl + 262144, bn1 + l * 256,
                                        wl + 393216, bn2 + l * 256);
    if (l == 0) { xin = x1; xout = x2; }
    else if (l == 1) { xin = x2; xout = x1; }
  }
  final_kernel<<<64, 64, 0, stream>>>(logt, xs, x1, x0, out);
}

// Round 7
// 693.159 us; speedup vs baseline: 1.0343x; 1.0343x over previous
//
#include <hip/hip_runtime.h>

typedef unsigned short ushort_t;
typedef __attribute__((ext_vector_type(8))) short s8v;
typedef __attribute__((ext_vector_type(4))) float f4v;
typedef __attribute__((ext_vector_type(4))) unsigned int u32x4;

#define NNODE 4096
#define HID 256
#define CR_L 5.0f      // COORDS_RANGE / L = 15/3
#define ASTR 528       // A-tile row stride in bytes (33*16: aligned, bank-uniform)
#define ASTR16 (16 * ASTR)
#define NSTR 1056      // node-kernel stage-1 stride (66*16)
#define NSTR16 (16 * NSTR)

__device__ __forceinline__ unsigned int cvt2(float lo, float hi) {
  unsigned int r;
  asm("v_cvt_pk_bf16_f32 %0, %1, %2" : "=v"(r) : "v"(lo), "v"(hi));
  return r;  // D[15:0]=lo, D[31:16]=hi, RNE
}
__device__ __forceinline__ ushort_t cvt1(float v) {
  unsigned int r;
  asm("v_cvt_pk_bf16_f32 %0, %1, %2" : "=v"(r) : "v"(v), "v"(v));
  return (ushort_t)r;
}
__device__ __forceinline__ float fast_rcp(float x) {
  float r;
  asm("v_rcp_f32 %0, %1" : "=v"(r) : "v"(x));
  return r;
}
__device__ __forceinline__ float silu_f(float v) { return v * fast_rcp(1.0f + __expf(-v)); }
__device__ __forceinline__ float sigm_f(float v) { return fast_rcp(1.0f + __expf(-v)); }

// ---- 8-wave edge-GEMM helpers: wave covers 32 cols (nt in {0,1}) ----
__device__ __forceinline__ void loadB2(s8v bd[2], const char* base, int q) {
#pragma unroll
  for (int nt = 0; nt < 2; ++nt)
    bd[nt] = *(const s8v*)(base + nt * 8192 + q * 64);
}
__device__ __forceinline__ void mfma_step2(const char* Ath, int q, const s8v bc[2], f4v acc[4][2]) {
  s8v a[4];
#pragma unroll
  for (int mt = 0; mt < 4; ++mt)
    a[mt] = *(const s8v*)(Ath + mt * ASTR16 + q * 64);
#pragma unroll
  for (int mt = 0; mt < 4; ++mt)
#pragma unroll
    for (int nt = 0; nt < 2; ++nt)
      acc[mt][nt] = __builtin_amdgcn_mfma_f32_16x16x32_bf16(a[mt], bc[nt], acc[mt][nt], 0, 0, 0);
}

// legacy direct-global gemm (proj/node kernels — off the critical path)
__device__ __forceinline__ void gemm64(const char* Ath, const ushort_t* Bth, f4v acc[4][4]) {
#pragma unroll
  for (int ks = 0; ks < 8; ++ks) {
    s8v a[4], bb[4];
#pragma unroll
    for (int mt = 0; mt < 4; ++mt)
      a[mt] = *(const s8v*)(Ath + mt * ASTR16 + ks * 64);
#pragma unroll
    for (int nt = 0; nt < 4; ++nt)
      bb[nt] = *(const s8v*)(Bth + nt * 4096 + ks * 32);
#pragma unroll
    for (int mt = 0; mt < 4; ++mt)
#pragma unroll
      for (int nt = 0; nt < 4; ++nt)
        acc[mt][nt] = __builtin_amdgcn_mfma_f32_16x16x32_bf16(a[mt], bb[nt], acc[mt][nt], 0, 0, 0);
  }
}

// ---------------- weight transpose + bf16 convert ----------------
__global__ __launch_bounds__(256) void wconv_kernel(
    const float* __restrict__ We1, const float* __restrict__ We2,
    const float* __restrict__ Wc1, const float* __restrict__ Wn1,
    const float* __restrict__ Wn2, ushort_t* __restrict__ wt) {
  int gid = blockIdx.x * 256 + threadIdx.x;          // < 1376256
  int l = gid / 458752;
  int r = gid - l * 458752;
  float v;
  if (r < 131072) {
    int part = r >> 16; int rr = r & 65535; int nn = rr >> 8, k = rr & 255;
    v = We1[(l * 513 + part * 256 + k) * 256 + nn];
  } else if (r < 196608) {
    int rr = r - 131072; int nn = rr >> 8, k = rr & 255;
    v = We2[(l * 256 + k) * 256 + nn];
  } else if (r < 262144) {
    int rr = r - 196608; int nn = rr >> 8, k = rr & 255;
    v = Wc1[(l * 256 + k) * 256 + nn];
  } else if (r < 393216) {
    int rr = r - 262144; int nn = rr >> 9, k = rr & 511;
    v = Wn1[(l * 512 + k) * 256 + nn];
  } else {
    int rr = r - 393216; int nn = rr >> 8, k = rr & 255;
    v = Wn2[(l * 256 + k) * 256 + nn];
  }
  wt[gid] = cvt1(v);
}

// ---------------- time embedding + preconditioning ----------------
__global__ __launch_bounds__(256) void embed_kernel(
    const float* __restrict__ logt, const float* __restrict__ xs,
    const float* __restrict__ Wemb, const float* __restrict__ bemb,
    float* __restrict__ h, float* __restrict__ x0) {
  __shared__ float te[128];
  const int b = blockIdx.x, tid = threadIdx.x;
  const float lt = logt[b];
  if (tid < 64) {
    float fr = powf(1e-4f, (float)tid * (1.0f / 64.0f));
    float ang = lt * 0.25f * fr;
    te[tid] = cosf(ang);
    te[tid + 64] = sinf(ang);
  }
  float tt = expf(lt);
  float cin = 1.0f / sqrtf(0.25f + tt * tt);
  if (tid < 192) x0[b * 192 + tid] = xs[b * 192 + tid] * cin;
  __syncthreads();
  float acc = bemb[tid];
  for (int k = 0; k < 128; ++k) acc += te[k] * Wemb[k * 256 + tid];
  float* hp = h + (b * 64) * 256 + tid;
#pragma unroll 4
  for (int nn = 0; nn < 64; ++nn) hp[nn * 256] = acc;
}

// ---------------- per-node projections: grid 128, one matmul per block ----------------
__global__ __launch_bounds__(256) void proj_kernel(
    const float* __restrict__ h, const ushort_t* __restrict__ Bt0,
    const ushort_t* __restrict__ Bt1, const float* __restrict__ be1,
    float* __restrict__ p_r, float* __restrict__ p_c) {
  __shared__ u32x4 AbV[64 * ASTR / 16];
  char* Ab = (char*)AbV;
  const int t = threadIdx.x, lane = t & 63, w = t >> 6;
  const int al = lane & 15, ag = lane >> 4;
  const int mat = blockIdx.x & 1;
  const int R0 = (blockIdx.x >> 1) * 64;
  {
    const int j = t & 63, cc = t >> 6;
    const float4* hv = (const float4*)(h + (R0 + j) * 256) + cc * 16;
    u32x4* wb = (u32x4*)(Ab + j * ASTR + cc * 128);
#pragma unroll
    for (int g = 0; g < 8; ++g) {
      float4 v0 = hv[g * 2], v1 = hv[g * 2 + 1];
      u32x4 q;
      q[0] = cvt2(v0.x, v0.y); q[1] = cvt2(v0.z, v0.w);
      q[2] = cvt2(v1.x, v1.y); q[3] = cvt2(v1.z, v1.w);
      wb[g] = q;
    }
  }
  __syncthreads();
  const char* Ath = Ab + al * ASTR + ag * 16;
  const ushort_t* Bth = (mat ? Bt1 : Bt0) + (w * 64 + al) * 256 + ag * 8;
  float* P = mat ? p_c : p_r;
  f4v acc[4][4];
#pragma unroll
  for (int mt = 0; mt < 4; ++mt)
#pragma unroll
    for (int nt = 0; nt < 4; ++nt) acc[mt][nt] = (f4v){0.f, 0.f, 0.f, 0.f};
  gemm64(Ath, Bth, acc);
#pragma unroll
  for (int mt = 0; mt < 4; ++mt)
#pragma unroll
    for (int nt = 0; nt < 4; ++nt) {
      int col = w * 64 + nt * 16 + al;
      float bias = mat ? 0.0f : be1[col];
#pragma unroll
      for (int r = 0; r < 4; ++r) {
        int row = mt * 16 + ag * 4 + r;
        P[(R0 + row) * 256 + col] = acc[mt][nt][r] + bias;
      }
    }
}

// ---------------- fused edge kernel: one block per node (its 63 out-edges) ----------------
// 8 waves x 32 cols; B global->reg 3-deep pipeline; XCD-swizzled blockIdx; 4 barriers.
__global__ __launch_bounds__(512, 4) void edge_kernel(
    const float* __restrict__ x_in, float* __restrict__ x_out,
    const float* __restrict__ p_r, const float* __restrict__ p_c,
    const float* __restrict__ w_rad,
    const ushort_t* __restrict__ We2t, const float* __restrict__ be2,
    const float* __restrict__ Wa, const float* __restrict__ ba,
    const ushort_t* __restrict__ Wc1t, const float* __restrict__ bc1,
    const float* __restrict__ Wc2, float* __restrict__ agg) {
  __shared__ u32x4 AbV[64 * ASTR / 16];   // 33 KB A-tile (m1, then m2)
  char* Ab = (char*)AbV;
  __shared__ float dn[64][3];
  __shared__ float red[8][64];

  const int t = threadIdx.x;
  // XCD swizzle: dispatch d -> XCD d%8; batches 8x..8x+7 all live on XCD x.
  const int node = ((blockIdx.x & 7) << 9) | (blockIdx.x >> 3);
  const int b = node >> 6, n = node & 63;
  const int lane = t & 63, w = t >> 6;          // w in [0,8): col strip w*32..+32
  const int al = lane & 15, ag = lane >> 4;

  const char* bWe2 = (const char*)We2t + ((w * 32 + al) * 256 + ag * 8) * 2;
  const char* bWc1 = (const char*)Wc1t + ((w * 32 + al) * 256 + ag * 8) * 2;

  s8v b0[2], b1[2], b2[2];
  loadB2(b0, bWe2, 0);   // prefetch GEMM1 panels 0..2 — hide under all of phase 1
  loadB2(b1, bWe2, 1);
  loadB2(b2, bWe2, 2);

  // ---- phase 1: geometry (redundant per wave) + m1 -> Ab (rows j, cols w*32..+32) ----
  {
    const int j = lane;
    const bool live = j < 63;
    const int cl = j < n ? j : j + 1;
    const int nb = (b << 6) + cl;
    const float xi0 = x_in[node * 3], xi1 = x_in[node * 3 + 1], xi2 = x_in[node * 3 + 2];
    const float d0 = xi0 - x_in[nb * 3], d1 = xi1 - x_in[nb * 3 + 1], d2 = xi2 - x_in[nb * 3 + 2];
    const float r2 = d0 * d0 + d1 * d1 + d2 * d2;
    const float inv = fast_rcp(sqrtf(r2 + 1e-8f) + 1.0f);
    if (t < 63) { dn[t][0] = d0 * inv; dn[t][1] = d1 * inv; dn[t][2] = d2 * inv; }
    const float rj = live ? r2 : 0.0f;
    const float4* prv = (const float4*)(p_r + (node << 8)) + w * 8;
    const float4* pcv = (const float4*)(p_c + (nb << 8)) + w * 8;
    const float4* wrv = (const float4*)w_rad + w * 8;
    u32x4* wb = (u32x4*)(Ab + j * ASTR + w * 64);
#pragma unroll
    for (int g = 0; g < 4; ++g) {
      u32x4 q = {0u, 0u, 0u, 0u};
      if (live) {
        float4 a0 = prv[g * 2], a1 = prv[g * 2 + 1];
        float4 bq = pcv[g * 2], b1q = pcv[g * 2 + 1];
        float4 w0 = wrv[g * 2], w1 = wrv[g * 2 + 1];
        float v0 = silu_f(a0.x + bq.x + rj * w0.x);
        float v1 = silu_f(a0.y + bq.y + rj * w0.y);
        float v2 = silu_f(a0.z + bq.z + rj * w0.z);
        float v3 = silu_f(a0.w + bq.w + rj * w0.w);
        float v4 = silu_f(a1.x + b1q.x + rj * w1.x);
        float v5 = silu_f(a1.y + b1q.y + rj * w1.y);
        float v6 = silu_f(a1.z + b1q.z + rj * w1.z);
        float v7 = silu_f(a1.w + b1q.w + rj * w1.w);
        q[0] = cvt2(v0, v1); q[1] = cvt2(v2, v3);
        q[2] = cvt2(v4, v5); q[3] = cvt2(v6, v7);
      }
      wb[g] = q;
    }
  }
  __syncthreads();   // S1: m1 visible

  const char* Ath = Ab + al * ASTR + ag * 16;

  // ---- GEMM1: g1 = m1 @ We2 — barrier-free, 3-deep reg-pipelined B ----
  f4v acc[4][2];
#pragma unroll
  for (int mt = 0; mt < 4; ++mt)
#pragma unroll
    for (int nt = 0; nt < 2; ++nt) acc[mt][nt] = (f4v){0.f, 0.f, 0.f, 0.f};
  mfma_step2(Ath, 0, b0, acc); loadB2(b0, bWe2, 3);
  mfma_step2(Ath, 1, b1, acc); loadB2(b1, bWe2, 4);
  mfma_step2(Ath, 2, b2, acc); loadB2(b2, bWe2, 5);
  mfma_step2(Ath, 3, b0, acc); loadB2(b0, bWe2, 6);
  mfma_step2(Ath, 4, b1, acc); loadB2(b1, bWe2, 7);
  mfma_step2(Ath, 5, b2, acc); loadB2(b2, bWc1, 0);   // prefetch GEMM2 panels
  mfma_step2(Ath, 6, b0, acc); loadB2(b0, bWc1, 1);
  mfma_step2(Ath, 7, b1, acc); loadB2(b1, bWc1, 2);

  // ---- epilogue1a (regs only): m2 = silu(g1+be2); attention partials + reduce ----
  {
    float bb2[2], wa4[2];
#pragma unroll
    for (int nt = 0; nt < 2; ++nt) {
      int col = w * 32 + nt * 16 + al;
      bb2[nt] = be2[col]; wa4[nt] = Wa[col];
    }
    float attp[4][4];
#pragma unroll
    for (int mt = 0; mt < 4; ++mt) {
#pragma unroll
      for (int r = 0; r < 4; ++r) attp[mt][r] = 0.0f;
#pragma unroll
      for (int nt = 0; nt < 2; ++nt) {
#pragma unroll
        for (int r = 0; r < 4; ++r) {
          float v = silu_f(acc[mt][nt][r] + bb2[nt]);
          acc[mt][nt][r] = v;
          attp[mt][r] += v * wa4[nt];
        }
      }
    }
#pragma unroll
    for (int off = 1; off < 16; off <<= 1)
#pragma unroll
      for (int mt = 0; mt < 4; ++mt)
#pragma unroll
        for (int r = 0; r < 4; ++r) attp[mt][r] += __shfl_xor(attp[mt][r], off);
    __syncthreads();   // S2: all waves done reading m1 from Ab
    // ---- epilogue1b: write m2 -> Ab (bf16) and att partials -> red ----
    char* mwb = Ab + (ag * 4) * ASTR + (w * 32 + al) * 2;
#pragma unroll
    for (int mt = 0; mt < 4; ++mt)
#pragma unroll
      for (int nt = 0; nt < 2; ++nt)
#pragma unroll
        for (int r = 0; r < 4; ++r)
          *(ushort_t*)(mwb + mt * ASTR16 + r * ASTR + nt * 32) = cvt1(acc[mt][nt][r]);
    if (al == 0) {
#pragma unroll
      for (int mt = 0; mt < 4; ++mt)
#pragma unroll
        for (int r = 0; r < 4; ++r) red[w][mt * 16 + ag * 4 + r] = attp[mt][r];
    }
  }
  __syncthreads();     // S3: m2 + red ready

  // ---- attention gate: EVERY wave computes att_reg redundantly (no barrier) ----
  float att_reg;
  {
    float s = red[0][lane] + red[1][lane] + red[2][lane] + red[3][lane] +
              red[4][lane] + red[5][lane] + red[6][lane] + red[7][lane] + ba[0];
    att_reg = (lane < 63) ? sigm_f(s) : 0.0f;   // mask padded row 63
  }

  // ---- agg column sums (att gathered via shfl from regs) ----
  {
    float aggp[2] = {0.f, 0.f};
#pragma unroll
    for (int mt = 0; mt < 4; ++mt) {
      float a0 = __shfl(att_reg, mt * 16 + ag * 4 + 0);
      float a1 = __shfl(att_reg, mt * 16 + ag * 4 + 1);
      float a2 = __shfl(att_reg, mt * 16 + ag * 4 + 2);
      float a3 = __shfl(att_reg, mt * 16 + ag * 4 + 3);
#pragma unroll
      for (int nt = 0; nt < 2; ++nt)
        aggp[nt] += a0 * acc[mt][nt][0] + a1 * acc[mt][nt][1] +
                    a2 * acc[mt][nt][2] + a3 * acc[mt][nt][3];
    }
#pragma unroll
    for (int nt = 0; nt < 2; ++nt) {
      aggp[nt] += __shfl_xor(aggp[nt], 16);
      aggp[nt] += __shfl_xor(aggp[nt], 32);
    }
    if (ag < 2)
      agg[(node << 8) + w * 32 + ag * 16 + al] = (ag == 0) ? aggp[0] : aggp[1];
  }

  // ---- GEMM2: g2 = m2 @ Wc1 — barrier-free (gate folded into epilogue) ----
#pragma unroll
  for (int mt = 0; mt < 4; ++mt)
#pragma unroll
    for (int nt = 0; nt < 2; ++nt) acc[mt][nt] = (f4v){0.f, 0.f, 0.f, 0.f};
  mfma_step2(Ath, 0, b2, acc); loadB2(b2, bWc1, 3);
  mfma_step2(Ath, 1, b0, acc); loadB2(b0, bWc1, 4);
  mfma_step2(Ath, 2, b1, acc); loadB2(b1, bWc1, 5);
  mfma_step2(Ath, 3, b2, acc); loadB2(b2, bWc1, 6);
  mfma_step2(Ath, 4, b0, acc); loadB2(b0, bWc1, 7);
  mfma_step2(Ath, 5, b1, acc);
  mfma_step2(Ath, 6, b2, acc);
  mfma_step2(Ath, 7, b0, acc);

  // ---- epilogue 2: s = silu(att*g2 + bc1); tr-partials = s . Wc2 ----
  {
    float b3[2], wc4[2];
#pragma unroll
    for (int nt = 0; nt < 2; ++nt) {
      int col = w * 32 + nt * 16 + al;
      b3[nt] = bc1[col]; wc4[nt] = Wc2[col];
    }
    float trp[4][4];
#pragma unroll
    for (int mt = 0; mt < 4; ++mt) {
      float a0 = __shfl(att_reg, mt * 16 + ag * 4 + 0);
      float a1 = __shfl(att_reg, mt * 16 + ag * 4 + 1);
      float a2 = __shfl(att_reg, mt * 16 + ag * 4 + 2);
      float a3 = __shfl(att_reg, mt * 16 + ag * 4 + 3);
#pragma unroll
      for (int r = 0; r < 4; ++r) trp[mt][r] = 0.0f;
#pragma unroll
      for (int nt = 0; nt < 2; ++nt) {
        trp[mt][0] += silu_f(a0 * acc[mt][nt][0] + b3[nt]) * wc4[nt];
        trp[mt][1] += silu_f(a1 * acc[mt][nt][1] + b3[nt]) * wc4[nt];
        trp[mt][2] += silu_f(a2 * acc[mt][nt][2] + b3[nt]) * wc4[nt];
        trp[mt][3] += silu_f(a3 * acc[mt][nt][3] + b3[nt]) * wc4[nt];
      }
    }
#pragma unroll
    for (int off = 1; off < 16; off <<= 1)
#pragma unroll
      for (int mt = 0; mt < 4; ++mt)
#pragma unroll
        for (int r = 0; r < 4; ++r) trp[mt][r] += __shfl_xor(trp[mt][r], off);
    if (al == 0) {
#pragma unroll
      for (int mt = 0; mt < 4; ++mt)
#pragma unroll
        for (int r = 0; r < 4; ++r) red[w][mt * 16 + ag * 4 + r] = trp[mt][r];
    }
  }
  __syncthreads();     // S4 (last): red2 ready

  // ---- fused tail (wave 0 only): tr = tanh(.)*cr ; x_out = x_in + sum dn*tr ----
  if (t < 64) {
    float s = red[0][t] + red[1][t] + red[2][t] + red[3][t] +
              red[4][t] + red[5][t] + red[6][t] + red[7][t];
    float vx = 0.f, vy = 0.f, vz = 0.f;
    if (t < 63) {
      float tj = tanhf(s) * CR_L;
      vx = dn[t][0] * tj; vy = dn[t][1] * tj; vz = dn[t][2] * tj;
    }
#pragma unroll
    for (int off = 1; off < 64; off <<= 1) {
      vx += __shfl_xor(vx, off);
      vy += __shfl_xor(vy, off);
      vz += __shfl_xor(vz, off);
    }
    if (t == 0) {
      x_out[node * 3 + 0] = x_in[node * 3 + 0] + vx;
      x_out[node * 3 + 1] = x_in[node * 3 + 1] + vy;
      x_out[node * 3 + 2] = x_in[node * 3 + 2] + vz;
    }
  }
}

// ---------------- node update: h += silu([h||agg]@Wn1+bn1)@Wn2+bn2 ----------------
__global__ __launch_bounds__(256) void node_kernel(
    float* __restrict__ h, const float* __restrict__ agg,
    const ushort_t* __restrict__ Wn1t, const float* __restrict__ bn1,
    const ushort_t* __restrict__ Wn2t, const float* __restrict__ bn2) {
  __shared__ u32x4 AbV[64 * NSTR / 16];   // 66KB: A1 [64][512]@1056B, reused as A2 [64][256]@528B
  char* Ab = (char*)AbV;
  const int t = threadIdx.x, lane = t & 63, w = t >> 6;
  const int al = lane & 15, ag = lane >> 4;
  const int R0 = blockIdx.x * 64;
  {
    const int j = t & 63, cc = t >> 6;
    u32x4* wb = (u32x4*)(Ab + j * NSTR + cc * 256);
#pragma unroll
    for (int g = 0; g < 16; ++g) {
      int c0 = cc * 128 + g * 8;
      const float* src = (c0 < 256) ? (h + (R0 + j) * 256 + c0)
                                    : (agg + (R0 + j) * 256 + (c0 - 256));
      float4 v0 = *(const float4*)src;
      float4 v1 = *(const float4*)(src + 4);
      u32x4 q;
      q[0] = cvt2(v0.x, v0.y); q[1] = cvt2(v0.z, v0.w);
      q[2] = cvt2(v1.x, v1.y); q[3] = cvt2(v1.z, v1.w);
      wb[g] = q;
    }
  }
  __syncthreads();
  // GEMM-A: K=512
  const char* AthN = Ab + al * NSTR + ag * 16;
  const ushort_t* BthA = Wn1t + (w * 64 + al) * 512 + ag * 8;
  f4v acc[4][4];
#pragma unroll
  for (int mt = 0; mt < 4; ++mt)
#pragma unroll
    for (int nt = 0; nt < 4; ++nt) acc[mt][nt] = (f4v){0.f, 0.f, 0.f, 0.f};
#pragma unroll
  for (int ks = 0; ks < 16; ++ks) {
    s8v a[4], bb[4];
#pragma unroll
    for (int mt = 0; mt < 4; ++mt)
      a[mt] = *(const s8v*)(AthN + mt * NSTR16 + ks * 64);
#pragma unroll
    for (int nt = 0; nt < 4; ++nt)
      bb[nt] = *(const s8v*)(BthA + nt * 8192 + ks * 32);
#pragma unroll
    for (int mt = 0; mt < 4; ++mt)
#pragma unroll
      for (int nt = 0; nt < 4; ++nt)
        acc[mt][nt] = __builtin_amdgcn_mfma_f32_16x16x32_bf16(a[mt], bb[nt], acc[mt][nt], 0, 0, 0);
  }
  __syncthreads();
  // u = silu(. + bn1) -> A2 (528B stride)
  {
    float bn1c[4];
#pragma unroll
    for (int nt = 0; nt < 4; ++nt) bn1c[nt] = bn1[w * 64 + nt * 16 + al];
    char* mwb = Ab + (ag * 4) * ASTR + (w * 64 + al) * 2;
#pragma unroll
    for (int mt = 0; mt < 4; ++mt)
#pragma unroll
      for (int nt = 0; nt < 4; ++nt)
#pragma unroll
        for (int r = 0; r < 4; ++r) {
          float v = silu_f(acc[mt][nt][r] + bn1c[nt]);
          *(ushort_t*)(mwb + mt * ASTR16 + r * ASTR + nt * 32) = cvt1(v);
        }
  }
  __syncthreads();
  // GEMM-B + residual
  const char* Ath2 = Ab + al * ASTR + ag * 16;
  const ushort_t* BthB = Wn2t + (w * 64 + al) * 256 + ag * 8;
#pragma unroll
  for (int mt = 0; mt < 4; ++mt)
#pragma unroll
    for (int nt = 0; nt < 4; ++nt) acc[mt][nt] = (f4v){0.f, 0.f, 0.f, 0.f};
  gemm64(Ath2, BthB, acc);
  {
    float bn2c[4];
#pragma unroll
    for (int nt = 0; nt < 4; ++nt) bn2c[nt] = bn2[w * 64 + nt * 16 + al];
#pragma unroll
    for (int mt = 0; mt < 4; ++mt)
#pragma unroll
      for (int nt = 0; nt < 4; ++nt) {
        int col = w * 64 + nt * 16 + al;
#pragma unroll
        for (int r = 0; r < 4; ++r) {
          int row = mt * 16 + ag * 4 + r;
          int idx = (R0 + row) * 256 + col;
          h[idx] = h[idx] + acc[mt][nt][r] + bn2c[nt];
        }
      }
  }
}

// ---------------- final: CoG removal + EDM output scaling ----------------
__global__ __launch_bounds__(64) void final_kernel(
    const float* __restrict__ logt, const float* __restrict__ xs,
    const float* __restrict__ xf, const float* __restrict__ x0,
    float* __restrict__ out) {
  const int b = blockIdx.x, t = threadIdx.x;
  float lt = logt[b], tt = expf(lt);
  float denom = 0.25f + tt * tt;
  float s1 = 0.25f / denom;
  float s2 = 0.5f * tt / sqrtf(denom);
  int node = b * 64 + t;
  float v0 = xf[node * 3 + 0] - x0[node * 3 + 0];
  float v1 = xf[node * 3 + 1] - x0[node * 3 + 1];
  float v2 = xf[node * 3 + 2] - x0[node * 3 + 2];
  float m0 = v0, m1 = v1, m2 = v2;
#pragma unroll
  for (int off = 1; off < 64; off <<= 1) {
    m0 += __shfl_xor(m0, off);
    m1 += __shfl_xor(m1, off);
    m2 += __shfl_xor(m2, off);
  }
  m0 *= (1.0f / 64.0f); m1 *= (1.0f / 64.0f); m2 *= (1.0f / 64.0f);
  out[b * 192 + t * 3 + 0] = xs[b * 192 + t * 3 + 0] * s1 + (v0 - m0) * s2;
  out[b * 192 + t * 3 + 1] = xs[b * 192 + t * 3 + 1] * s1 + (v1 - m1) * s2;
  out[b * 192 + t * 3 + 2] = xs[b * 192 + t * 3 + 2] * s1 + (v2 - m2) * s2;
}

extern "C" void kernel_launch(void* const* d_in, const int* in_sizes, int n_in,
                              void* d_out, int out_size, void* d_ws, size_t ws_size,
                              hipStream_t stream) {
  const float* logt = (const float*)d_in[0];
  const float* xs   = (const float*)d_in[1];
  const float* Wemb = (const float*)d_in[2];
  const float* bemb = (const float*)d_in[3];
  const float* We1  = (const float*)d_in[4];
  const float* be1  = (const float*)d_in[5];
  const float* We2  = (const float*)d_in[6];
  const float* be2  = (const float*)d_in[7];
  const float* Wa   = (const float*)d_in[8];
  const float* ba   = (const float*)d_in[9];
  const float* Wn1  = (const float*)d_in[10];
  const float* bn1  = (const float*)d_in[11];
  const float* Wn2  = (const float*)d_in[12];
  const float* bn2  = (const float*)d_in[13];
  const float* Wc1  = (const float*)d_in[14];
  const float* bc1  = (const float*)d_in[15];
  const float* Wc2  = (const float*)d_in[16];
  float* out = (float*)d_out;

  float* h   = (float*)d_ws;            // 4096*256
  float* pr  = h   + NNODE * HID;
  float* pc  = pr  + NNODE * HID;
  float* agg = pc  + NNODE * HID;
  float* x0  = agg + NNODE * HID;
  float* x1  = x0  + 12288;
  float* x2  = x1  + 12288;
  ushort_t* wt = (ushort_t*)(x2 + 12288);   // 1376256 bf16

  wconv_kernel<<<5376, 256, 0, stream>>>(We1, We2, Wc1, Wn1, Wn2, wt);
  embed_kernel<<<64, 256, 0, stream>>>(logt, xs, Wemb, bemb, h, x0);

  const float* xin = x0;
  float* xout = x1;
  for (int l = 0; l < 3; ++l) {
    const ushort_t* wl = wt + l * 458752;
    proj_kernel<<<128, 256, 0, stream>>>(h, wl, wl + 65536, be1 + l * 256, pr, pc);
    edge_kernel<<<4096, 512, 0, stream>>>(
        xin, xout, pr, pc,
        We1 + (l * 513 + 512) * 256,
        wl + 131072, be2 + l * 256,
        Wa + l * 256, ba + l,
        wl + 196608, bc1 + l * 256, Wc2 + l * 256, agg);
    node_kernel<<<64, 256, 0, stream>>>(h, agg, wl + 262144, bn1 + l * 256,
                                        wl + 393216, bn2 + l * 256);
    if (l == 0) { xin = x1; xout = x2; }
    else if (l == 1) { xin = x2; xout = x1; }
  }
  final_kernel<<<64, 64, 0, stream>>>(logt, xs, x1, x0, out);
}